// Round 1
// baseline (5150.970 us; speedup 1.0000x reference)
//
#include <hip/hip_runtime.h>
#include <math.h>

// Restarted GMRES(16), 4 cycles, Helmholtz (-lap + 0.3) on 1024x1024 periodic fp32.
// Baseline: kernel-per-phase, two-stage deterministic reductions, device-resident
// scalars in workspace (graph-capture safe).

#define NGRID 1024
#define NE (NGRID*NGRID)
#define TPB 256
#define NBLK 1024          // NE / (TPB*4)
#define KMAX 17            // RESTART+1
#define RST 16
#define NCYC 4

// scalar slots (floats) in scal area
#define SC_H    0          // h[0..16]
#define SC_H2   32         // h2[0..16]
#define SC_BETA 64
#define SC_INV  65         // current 1/(norm+eps) scale
#define SC_HM   96         // Hm[k][j] = SC_HM + k*RST + j   (17x16)
#define SC_Y    384        // y[0..15]

__device__ __forceinline__ float4 ld4(const float* p) {
  return *reinterpret_cast<const float4*>(p);
}
__device__ __forceinline__ void st4(float* p, float4 v) {
  *reinterpret_cast<float4*>(p) = v;
}
__device__ __forceinline__ float dot4(float4 a, float4 b) {
  return a.x*b.x + a.y*b.y + a.z*b.z + a.w*b.w;
}

// A(u) = -lap(u) + 0.3*u at 4 consecutive elements starting at (i, jc); periodic.
// Mimic reference rounding: lap = (nbrs - 4u); out = K2*u - lap
__device__ __forceinline__ float4 helmholtz4(const float* __restrict__ u, int i, int jc) {
  int elem = i*NGRID + jc;
  int up = ((i + NGRID - 1) & (NGRID-1))*NGRID + jc;
  int dn = ((i + 1) & (NGRID-1))*NGRID + jc;
  float4 c = ld4(u + elem);
  float4 a = ld4(u + up);
  float4 b = ld4(u + dn);
  float lf = u[i*NGRID + ((jc + NGRID - 1) & (NGRID-1))];
  float rt = u[i*NGRID + ((jc + 4) & (NGRID-1))];
  float4 o;
  float lapx = (a.x + b.x + lf  + c.y) - 4.0f*c.x;
  float lapy = (a.y + b.y + c.x + c.z) - 4.0f*c.y;
  float lapz = (a.z + b.z + c.y + c.w) - 4.0f*c.z;
  float lapw = (a.w + b.w + c.z + rt ) - 4.0f*c.w;
  o.x = 0.3f*c.x - lapx;
  o.y = 0.3f*c.y - lapy;
  o.z = 0.3f*c.z - lapz;
  o.w = 0.3f*c.w - lapw;
  return o;
}

// r = b - A(x); write r to w; partial sum of r.r -> part[16*NBLK + blk]
__global__ __launch_bounds__(TPB)
void k_resid(const float* __restrict__ b, const float* __restrict__ x,
             float* __restrict__ w, float* __restrict__ part) {
  int t = blockIdx.x*TPB + threadIdx.x;
  int elem = t*4;
  int i = elem >> 10;
  int jc = elem & (NGRID-1);
  float4 a4 = helmholtz4(x, i, jc);
  float4 b4 = ld4(b + elem);
  float4 r4;
  r4.x = b4.x - a4.x; r4.y = b4.y - a4.y; r4.z = b4.z - a4.z; r4.w = b4.w - a4.w;
  st4(w + elem, r4);
  float s = dot4(r4, r4);
  #pragma unroll
  for (int off = 32; off; off >>= 1) s += __shfl_down(s, off);
  __shared__ float lds[4];
  int lane = threadIdx.x & 63, wv = threadIdx.x >> 6;
  if (lane == 0) lds[wv] = s;
  __syncthreads();
  if (threadIdx.x == 0)
    part[16*NBLK + blockIdx.x] = lds[0] + lds[1] + lds[2] + lds[3];
}

// beta = sqrt(sum part norm slot); scal[BETA], scal[INV] = 1/(beta+eps)
__global__ __launch_bounds__(TPB)
void k_finish_beta(const float* __restrict__ part, float* __restrict__ scal) {
  float s = 0.f;
  for (int m = threadIdx.x; m < NBLK; m += TPB) s += part[16*NBLK + m];
  #pragma unroll
  for (int off = 32; off; off >>= 1) s += __shfl_down(s, off);
  __shared__ float lds[4];
  int lane = threadIdx.x & 63, wv = threadIdx.x >> 6;
  if (lane == 0) lds[wv] = s;
  __syncthreads();
  if (threadIdx.x == 0) {
    float beta = sqrtf(lds[0] + lds[1] + lds[2] + lds[3]);
    scal[SC_BETA] = beta;
    scal[SC_INV] = 1.0f / (beta + 1e-12f);
  }
}

// dst = src * scal[SC_INV]
__global__ __launch_bounds__(TPB)
void k_scale(const float* __restrict__ src, float* __restrict__ dst,
             const float* __restrict__ scal) {
  float inv = scal[SC_INV];
  int elem = (blockIdx.x*TPB + threadIdx.x)*4;
  float4 v = ld4(src + elem);
  v.x *= inv; v.y *= inv; v.z *= inv; v.w *= inv;
  st4(dst + elem, v);
}

// w = A(V[j]); partial dots h[k] = V[k].w for k<=j
__global__ __launch_bounds__(TPB)
void k_stencil_dots(const float* __restrict__ V, int j,
                    float* __restrict__ w, float* __restrict__ part) {
  int t = blockIdx.x*TPB + threadIdx.x;
  int elem = t*4;
  int i = elem >> 10;
  int jc = elem & (NGRID-1);
  const float* u = V + (size_t)j*NE;
  float4 w4 = helmholtz4(u, i, jc);
  st4(w + elem, w4);
  __shared__ float lds[KMAX][4];
  int lane = threadIdx.x & 63, wv = threadIdx.x >> 6;
  #pragma unroll
  for (int k = 0; k < KMAX; ++k) {
    if (k <= j) {
      float s = dot4(ld4(V + (size_t)k*NE + elem), w4);
      #pragma unroll
      for (int off = 32; off; off >>= 1) s += __shfl_down(s, off);
      if (lane == 0) lds[k][wv] = s;
    }
  }
  __syncthreads();
  int k = threadIdx.x;
  if (k < KMAX && k <= j)
    part[k*NBLK + blockIdx.x] = lds[k][0] + lds[k][1] + lds[k][2] + lds[k][3];
}

// reduce part[k][*] -> out[k] for k<=j
__global__ __launch_bounds__(TPB)
void k_finish_dots(const float* __restrict__ part, int j, float* __restrict__ out) {
  __shared__ float lds[4];
  int lane = threadIdx.x & 63, wv = threadIdx.x >> 6;
  for (int k = 0; k <= j; ++k) {
    float s = 0.f;
    for (int m = threadIdx.x; m < NBLK; m += TPB) s += part[k*NBLK + m];
    #pragma unroll
    for (int off = 32; off; off >>= 1) s += __shfl_down(s, off);
    if (lane == 0) lds[wv] = s;
    __syncthreads();
    if (threadIdx.x == 0) out[k] = lds[0] + lds[1] + lds[2] + lds[3];
    __syncthreads();
  }
}

// w -= sum_{k<=j} h[k] V[k]; partial dots h2[k] = V[k].w_new (V cached in regs)
__global__ __launch_bounds__(TPB)
void k_proj_dots(const float* __restrict__ V, int j, float* __restrict__ w,
                 const float* __restrict__ h, float* __restrict__ part) {
  int t = blockIdx.x*TPB + threadIdx.x;
  int elem = t*4;
  float4 w4 = ld4(w + elem);
  float4 vc[KMAX];
  #pragma unroll
  for (int k = 0; k < KMAX; ++k) {
    if (k <= j) {
      vc[k] = ld4(V + (size_t)k*NE + elem);
      float hk = h[k];
      w4.x -= hk*vc[k].x; w4.y -= hk*vc[k].y; w4.z -= hk*vc[k].z; w4.w -= hk*vc[k].w;
    }
  }
  st4(w + elem, w4);
  __shared__ float lds[KMAX][4];
  int lane = threadIdx.x & 63, wv = threadIdx.x >> 6;
  #pragma unroll
  for (int k = 0; k < KMAX; ++k) {
    if (k <= j) {
      float s = dot4(vc[k], w4);
      #pragma unroll
      for (int off = 32; off; off >>= 1) s += __shfl_down(s, off);
      if (lane == 0) lds[k][wv] = s;
    }
  }
  __syncthreads();
  int k = threadIdx.x;
  if (k < KMAX && k <= j)
    part[k*NBLK + blockIdx.x] = lds[k][0] + lds[k][1] + lds[k][2] + lds[k][3];
}

// w -= sum_{k<=j} h2[k] V[k]; partial norm w.w -> part[16*NBLK + blk]
__global__ __launch_bounds__(TPB)
void k_proj_norm(const float* __restrict__ V, int j, float* __restrict__ w,
                 const float* __restrict__ h2, float* __restrict__ part) {
  int t = blockIdx.x*TPB + threadIdx.x;
  int elem = t*4;
  float4 w4 = ld4(w + elem);
  #pragma unroll
  for (int k = 0; k < KMAX; ++k) {
    if (k <= j) {
      float hk = h2[k];
      float4 v4 = ld4(V + (size_t)k*NE + elem);
      w4.x -= hk*v4.x; w4.y -= hk*v4.y; w4.z -= hk*v4.z; w4.w -= hk*v4.w;
    }
  }
  st4(w + elem, w4);
  float s = dot4(w4, w4);
  #pragma unroll
  for (int off = 32; off; off >>= 1) s += __shfl_down(s, off);
  __shared__ float lds[4];
  int lane = threadIdx.x & 63, wv = threadIdx.x >> 6;
  if (lane == 0) lds[wv] = s;
  __syncthreads();
  if (threadIdx.x == 0)
    part[16*NBLK + blockIdx.x] = lds[0] + lds[1] + lds[2] + lds[3];
}

// hn = sqrt(norm); write Hm[:,j]; scal[INV]=1/(hn+eps)
__global__ __launch_bounds__(64)
void k_finish_col(const float* __restrict__ part, int j, float* __restrict__ scal) {
  float s = 0.f;
  for (int m = threadIdx.x; m < NBLK; m += 64) s += part[16*NBLK + m];
  #pragma unroll
  for (int off = 32; off; off >>= 1) s += __shfl_down(s, off);
  __shared__ float sh_hn;
  if (threadIdx.x == 0) {
    float hn = sqrtf(s);
    sh_hn = hn;
    scal[SC_INV] = 1.0f / (hn + 1e-12f);
  }
  __syncthreads();
  int k = threadIdx.x;
  if (k < KMAX) {
    float v = 0.0f;
    if (k <= j)      v = scal[SC_H + k] + scal[SC_H2 + k];
    else if (k == j+1) v = sh_hn;
    scal[SC_HM + k*RST + j] = v;
  }
}

// tiny 16x16 normal-equations solve (single thread)
__global__ void k_solve(float* __restrict__ scal) {
  if (threadIdx.x != 0 || blockIdx.x != 0) return;
  const float* Hm = scal + SC_HM;
  float beta = scal[SC_BETA];
  float M[RST][RST+1];
  for (int a = 0; a < RST; ++a) {
    for (int b = 0; b < RST; ++b) {
      float s = 0.f;
      for (int k = 0; k < KMAX; ++k) s += Hm[k*RST + a]*Hm[k*RST + b];
      M[a][b] = s + (a == b ? 1e-12f : 0.f);
    }
    M[a][RST] = beta * Hm[a];   // beta * Hm[0][a]
  }
  // Gaussian elimination, partial pivoting
  for (int c = 0; c < RST; ++c) {
    int p = c; float mx = fabsf(M[c][c]);
    for (int r = c+1; r < RST; ++r) { float v = fabsf(M[r][c]); if (v > mx) { mx = v; p = r; } }
    if (p != c) for (int cc = c; cc <= RST; ++cc) { float tmp = M[c][cc]; M[c][cc] = M[p][cc]; M[p][cc] = tmp; }
    float pinv = 1.0f / M[c][c];
    for (int r = c+1; r < RST; ++r) {
      float f = M[r][c]*pinv;
      for (int cc = c; cc <= RST; ++cc) M[r][cc] -= f*M[c][cc];
    }
  }
  float y[RST];
  for (int c = RST-1; c >= 0; --c) {
    float s = M[c][RST];
    for (int cc = c+1; cc < RST; ++cc) s -= M[c][cc]*y[cc];
    y[c] = s / M[c][c];
  }
  for (int k = 0; k < RST; ++k) scal[SC_Y + k] = y[k];
}

// x += sum_{k<16} y[k] V[k]
__global__ __launch_bounds__(TPB)
void k_update_x(const float* __restrict__ V, const float* __restrict__ scal,
                float* __restrict__ x) {
  int elem = (blockIdx.x*TPB + threadIdx.x)*4;
  float4 acc = ld4(x + elem);
  #pragma unroll
  for (int k = 0; k < RST; ++k) {
    float yk = scal[SC_Y + k];
    float4 v = ld4(V + (size_t)k*NE + elem);
    acc.x += yk*v.x; acc.y += yk*v.y; acc.z += yk*v.z; acc.w += yk*v.w;
  }
  st4(x + elem, acc);
}

extern "C" void kernel_launch(void* const* d_in, const int* in_sizes, int n_in,
                              void* d_out, int out_size, void* d_ws, size_t ws_size,
                              hipStream_t stream) {
  const float* b     = (const float*)d_in[0];   // source
  const float* guess = (const float*)d_in[1];   // initial guess (zeros)
  float* x  = (float*)d_out;
  float* ws = (float*)d_ws;

  float* V    = ws;                                  // 17 * NE
  float* w    = ws + (size_t)KMAX*NE;                // NE
  float* part = ws + (size_t)(KMAX+1)*NE;            // KMAX * NBLK
  float* scal = part + (size_t)KMAX*NBLK;            // 512 floats

  // x = guess
  hipMemcpyAsync(x, guess, (size_t)NE*sizeof(float), hipMemcpyDeviceToDevice, stream);

  dim3 g(NBLK), blk(TPB);
  for (int cyc = 0; cyc < NCYC; ++cyc) {
    k_resid<<<g, blk, 0, stream>>>(b, x, w, part);
    k_finish_beta<<<1, blk, 0, stream>>>(part, scal);
    k_scale<<<g, blk, 0, stream>>>(w, V /*V[0]*/, scal);
    for (int j = 0; j < RST; ++j) {
      k_stencil_dots<<<g, blk, 0, stream>>>(V, j, w, part);
      k_finish_dots<<<1, blk, 0, stream>>>(part, j, scal + SC_H);
      k_proj_dots<<<g, blk, 0, stream>>>(V, j, w, scal + SC_H, part);
      k_finish_dots<<<1, blk, 0, stream>>>(part, j, scal + SC_H2);
      k_proj_norm<<<g, blk, 0, stream>>>(V, j, w, scal + SC_H2, part);
      k_finish_col<<<1, 64, 0, stream>>>(part, j, scal);
      k_scale<<<g, blk, 0, stream>>>(w, V + (size_t)(j+1)*NE, scal);
    }
    k_solve<<<1, 64, 0, stream>>>(scal);
    k_update_x<<<g, blk, 0, stream>>>(V, scal, x);
  }
}

// Round 2
// 2128.372 us; speedup vs baseline: 2.4201x; 2.4201x over previous
//
#include <hip/hip_runtime.h>
#include <math.h>

// Restarted GMRES(16), 4 cycles, Helmholtz (-lap + 0.3) on 1024x1024 periodic fp32.
// Round 2: no single-block finish kernels (each big kernel redundantly reduces the
// partials it needs), normalization fused into the stencil kernel (w ping-pong),
// kernels templated on j. 51 dispatches/cycle (was 117).

#define NGRID 1024
#define NE (NGRID*NGRID)
#define TPB 256
#define NBLK 1024          // NE / (TPB*4)
#define KMAX 17            // RESTART+1
#define RST 16
#define NCYC 4

// scalar slots (floats) in scal area
#define SC_HJ   0                  // h[j][k]  : j*KMAX + k   (16x17)
#define SC_H2J  288                // h2[j][k] : j*KMAX + k   (16x17)
#define SC_HN   576                // hn[j] = ||w_{j-1}||, j=1..15
#define SC_BETA 600
#define SC_Y    608                // y[0..15]

__device__ __forceinline__ float4 ld4(const float* p) {
  return *reinterpret_cast<const float4*>(p);
}
__device__ __forceinline__ void st4(float* p, float4 v) {
  *reinterpret_cast<float4*>(p) = v;
}
__device__ __forceinline__ float dot4(float4 a, float4 b) {
  return a.x*b.x + a.y*b.y + a.z*b.z + a.w*b.w;
}

// A(u) at 4 consecutive elements starting at (i, jc); periodic.
__device__ __forceinline__ float4 helmholtz4(const float* __restrict__ u, int i, int jc) {
  int elem = i*NGRID + jc;
  int up = ((i + NGRID - 1) & (NGRID-1))*NGRID + jc;
  int dn = ((i + 1) & (NGRID-1))*NGRID + jc;
  float4 c = ld4(u + elem);
  float4 a = ld4(u + up);
  float4 b = ld4(u + dn);
  float lf = u[i*NGRID + ((jc + NGRID - 1) & (NGRID-1))];
  float rt = u[i*NGRID + ((jc + 4) & (NGRID-1))];
  float4 o;
  o.x = 0.3f*c.x - ((a.x + b.x + lf  + c.y) - 4.0f*c.x);
  o.y = 0.3f*c.y - ((a.y + b.y + c.x + c.z) - 4.0f*c.y);
  o.z = 0.3f*c.z - ((a.z + b.z + c.y + c.w) - 4.0f*c.z);
  o.w = 0.3f*c.w - ((a.w + b.w + c.z + rt ) - 4.0f*c.w);
  return o;
}

// all blocks redundantly reduce ncols columns of part (NBLK floats each) into sh_out
__device__ __forceinline__ void reduce_cols(const float* __restrict__ part,
                                            int ncols, float* sh_out) {
  int wv = threadIdx.x >> 6, lane = threadIdx.x & 63;
  for (int c = wv; c < ncols; c += (TPB/64)) {
    const float* col = part + c*NBLK;
    float s = 0.f;
    #pragma unroll
    for (int m = 0; m < NBLK/64; ++m) s += col[lane + m*64];
    #pragma unroll
    for (int off = 32; off; off >>= 1) s += __shfl_down(s, off);
    if (lane == 0) sh_out[c] = s;
  }
  __syncthreads();
}

// r = b - A(x); w = r; partial norm -> partN
__global__ __launch_bounds__(TPB)
void k_resid(const float* __restrict__ b, const float* __restrict__ x,
             float* __restrict__ w, float* __restrict__ partN) {
  int t = blockIdx.x*TPB + threadIdx.x;
  int elem = t*4;
  int i = elem >> 10, jc = elem & (NGRID-1);
  float4 a4 = helmholtz4(x, i, jc);
  float4 b4 = ld4(b + elem);
  float4 r4;
  r4.x = b4.x - a4.x; r4.y = b4.y - a4.y; r4.z = b4.z - a4.z; r4.w = b4.w - a4.w;
  st4(w + elem, r4);
  float s = dot4(r4, r4);
  #pragma unroll
  for (int off = 32; off; off >>= 1) s += __shfl_down(s, off);
  __shared__ float lds[4];
  int lane = threadIdx.x & 63, wv = threadIdx.x >> 6;
  if (lane == 0) lds[wv] = s;
  __syncthreads();
  if (threadIdx.x == 0)
    partN[blockIdx.x] = lds[0] + lds[1] + lds[2] + lds[3];
}

// S<J>: reduce partN -> inv; V[J] = win*inv; wout = A(win*inv);
//       partial dots h[k] = V[k].wout (k<=J) -> partA
template<int J>
__global__ __launch_bounds__(TPB)
void k_S(const float* __restrict__ win, float* __restrict__ wout,
         float* __restrict__ V, const float* __restrict__ partN,
         float* __restrict__ partA, float* __restrict__ scal) {
  __shared__ float sh_nrm;
  int lane = threadIdx.x & 63, wv = threadIdx.x >> 6;
  if (wv == 0) {
    float s = 0.f;
    #pragma unroll
    for (int m = 0; m < NBLK/64; ++m) s += partN[lane + m*64];
    #pragma unroll
    for (int off = 32; off; off >>= 1) s += __shfl_down(s, off);
    if (lane == 0) sh_nrm = s;
  }
  __syncthreads();
  float hn = sqrtf(sh_nrm);
  float inv = 1.0f / (hn + 1e-12f);
  if (blockIdx.x == 0 && threadIdx.x == 0) {
    if (J == 0) scal[SC_BETA] = hn;
    else        scal[SC_HN + J] = hn;
  }
  int t = blockIdx.x*TPB + threadIdx.x;
  int elem = t*4;
  int i = elem >> 10, jc = elem & (NGRID-1);
  // load stencil of win, scale inputs by inv first (bit-matches A(round(w*inv)))
  float4 c  = ld4(win + elem);
  float4 a  = ld4(win + ((i + NGRID-1)&(NGRID-1))*NGRID + jc);
  float4 bb = ld4(win + ((i + 1)&(NGRID-1))*NGRID + jc);
  float lf = win[i*NGRID + ((jc + NGRID-1)&(NGRID-1))] * inv;
  float rt = win[i*NGRID + ((jc + 4)&(NGRID-1))] * inv;
  c.x*=inv; c.y*=inv; c.z*=inv; c.w*=inv;
  a.x*=inv; a.y*=inv; a.z*=inv; a.w*=inv;
  bb.x*=inv; bb.y*=inv; bb.z*=inv; bb.w*=inv;
  float4 vj = c;
  st4(V + (size_t)J*NE + elem, vj);
  float4 aw;
  aw.x = 0.3f*c.x - ((a.x + bb.x + lf  + c.y) - 4.0f*c.x);
  aw.y = 0.3f*c.y - ((a.y + bb.y + c.x + c.z) - 4.0f*c.y);
  aw.z = 0.3f*c.z - ((a.z + bb.z + c.y + c.w) - 4.0f*c.z);
  aw.w = 0.3f*c.w - ((a.w + bb.w + c.z + rt ) - 4.0f*c.w);
  st4(wout + elem, aw);
  __shared__ float lds[KMAX][4];
  #pragma unroll
  for (int k = 0; k <= J; ++k) {
    float4 vk = (k == J) ? vj : ld4(V + (size_t)k*NE + elem);
    float s = dot4(vk, aw);
    #pragma unroll
    for (int off = 32; off; off >>= 1) s += __shfl_down(s, off);
    if (lane == 0) lds[k][wv] = s;
  }
  __syncthreads();
  if (threadIdx.x <= J)
    partA[threadIdx.x*NBLK + blockIdx.x] =
      lds[threadIdx.x][0] + lds[threadIdx.x][1] + lds[threadIdx.x][2] + lds[threadIdx.x][3];
}

// P<J>: reduce partA -> h; w -= h.V; partial dots h2 -> partB; persist h
template<int J>
__global__ __launch_bounds__(TPB)
void k_P(float* __restrict__ w, const float* __restrict__ V,
         const float* __restrict__ partA, float* __restrict__ partB,
         float* __restrict__ scal) {
  __shared__ float sh_h[KMAX];
  reduce_cols(partA, J+1, sh_h);
  if (blockIdx.x == 0 && threadIdx.x <= J)
    scal[SC_HJ + J*KMAX + threadIdx.x] = sh_h[threadIdx.x];
  int elem = (blockIdx.x*TPB + threadIdx.x)*4;
  float4 w4 = ld4(w + elem);
  float4 vc[J+1];
  #pragma unroll
  for (int k = 0; k <= J; ++k) {
    vc[k] = ld4(V + (size_t)k*NE + elem);
    float hk = sh_h[k];
    w4.x -= hk*vc[k].x; w4.y -= hk*vc[k].y; w4.z -= hk*vc[k].z; w4.w -= hk*vc[k].w;
  }
  st4(w + elem, w4);
  __shared__ float lds[KMAX][4];
  int lane = threadIdx.x & 63, wv = threadIdx.x >> 6;
  #pragma unroll
  for (int k = 0; k <= J; ++k) {
    float s = dot4(vc[k], w4);
    #pragma unroll
    for (int off = 32; off; off >>= 1) s += __shfl_down(s, off);
    if (lane == 0) lds[k][wv] = s;
  }
  __syncthreads();
  if (threadIdx.x <= J)
    partB[threadIdx.x*NBLK + blockIdx.x] =
      lds[threadIdx.x][0] + lds[threadIdx.x][1] + lds[threadIdx.x][2] + lds[threadIdx.x][3];
}

// Q<J>: reduce partB -> h2; w -= h2.V; partial norm -> partN; persist h2
template<int J>
__global__ __launch_bounds__(TPB)
void k_Q(float* __restrict__ w, const float* __restrict__ V,
         const float* __restrict__ partB, float* __restrict__ partN,
         float* __restrict__ scal) {
  __shared__ float sh_h2[KMAX];
  reduce_cols(partB, J+1, sh_h2);
  if (blockIdx.x == 0 && threadIdx.x <= J)
    scal[SC_H2J + J*KMAX + threadIdx.x] = sh_h2[threadIdx.x];
  int elem = (blockIdx.x*TPB + threadIdx.x)*4;
  float4 w4 = ld4(w + elem);
  #pragma unroll
  for (int k = 0; k <= J; ++k) {
    float4 v4 = ld4(V + (size_t)k*NE + elem);
    float hk = sh_h2[k];
    w4.x -= hk*v4.x; w4.y -= hk*v4.y; w4.z -= hk*v4.z; w4.w -= hk*v4.w;
  }
  st4(w + elem, w4);
  float s = dot4(w4, w4);
  #pragma unroll
  for (int off = 32; off; off >>= 1) s += __shfl_down(s, off);
  __shared__ float ldsn[4];
  int lane = threadIdx.x & 63, wv = threadIdx.x >> 6;
  if (lane == 0) ldsn[wv] = s;
  __syncthreads();
  if (threadIdx.x == 0)
    partN[blockIdx.x] = ldsn[0] + ldsn[1] + ldsn[2] + ldsn[3];
}

// build Hm, solve 16x16 normal equations -> y
__global__ __launch_bounds__(256)
void k_solve(const float* __restrict__ partN, float* __restrict__ scal) {
  __shared__ float Hm[KMAX][RST];
  __shared__ float M[RST][RST+1];
  __shared__ float sh_n;
  int t = threadIdx.x;
  if (t < 64) {
    float s = 0.f;
    #pragma unroll
    for (int m = 0; m < NBLK/64; ++m) s += partN[t + m*64];
    #pragma unroll
    for (int off = 32; off; off >>= 1) s += __shfl_down(s, off);
    if (t == 0) sh_n = s;
  }
  __syncthreads();
  for (int idx = t; idx < KMAX*RST; idx += 256) {
    int k = idx / RST, j = idx % RST;
    float v = 0.f;
    if (k <= j)        v = scal[SC_HJ + j*KMAX + k] + scal[SC_H2J + j*KMAX + k];
    else if (k == j+1) v = (j < RST-1) ? scal[SC_HN + j + 1] : sqrtf(sh_n);
    Hm[k][j] = v;
  }
  __syncthreads();
  {
    int a = t >> 4, b = t & 15;
    float s = 0.f;
    #pragma unroll
    for (int k = 0; k < KMAX; ++k) s += Hm[k][a]*Hm[k][b];
    M[a][b] = s + (a == b ? 1e-12f : 0.f);
  }
  __syncthreads();
  if (t < RST) M[t][RST] = scal[SC_BETA] * Hm[0][t];
  __syncthreads();
  for (int c = 0; c < RST; ++c) {
    if (t == 0) {
      int p = c; float mx = fabsf(M[c][c]);
      for (int r = c+1; r < RST; ++r) { float v = fabsf(M[r][c]); if (v > mx) { mx = v; p = r; } }
      if (p != c) for (int cc = c; cc <= RST; ++cc) { float tmp = M[c][cc]; M[c][cc] = M[p][cc]; M[p][cc] = tmp; }
    }
    __syncthreads();
    if (t > c && t < RST) {
      float f = M[t][c] / M[c][c];
      for (int cc = c; cc <= RST; ++cc) M[t][cc] -= f*M[c][cc];
    }
    __syncthreads();
  }
  if (t == 0) {
    float y[RST];
    for (int c = RST-1; c >= 0; --c) {
      float s = M[c][RST];
      for (int cc = c+1; cc < RST; ++cc) s -= M[c][cc]*y[cc];
      y[c] = s / M[c][c];
    }
    for (int k = 0; k < RST; ++k) scal[SC_Y + k] = y[k];
  }
}

// x += sum_k y[k] V[k]
__global__ __launch_bounds__(TPB)
void k_update_x(const float* __restrict__ V, const float* __restrict__ scal,
                float* __restrict__ x) {
  int elem = (blockIdx.x*TPB + threadIdx.x)*4;
  float4 acc = ld4(x + elem);
  #pragma unroll
  for (int k = 0; k < RST; ++k) {
    float yk = scal[SC_Y + k];
    float4 v = ld4(V + (size_t)k*NE + elem);
    acc.x += yk*v.x; acc.y += yk*v.y; acc.z += yk*v.z; acc.w += yk*v.w;
  }
  st4(x + elem, acc);
}

extern "C" void kernel_launch(void* const* d_in, const int* in_sizes, int n_in,
                              void* d_out, int out_size, void* d_ws, size_t ws_size,
                              hipStream_t stream) {
  const float* b     = (const float*)d_in[0];   // source
  const float* guess = (const float*)d_in[1];   // initial guess (zeros)
  float* x  = (float*)d_out;
  float* ws = (float*)d_ws;

  float* V     = ws;                                  // 16 * NE  (V[16] never needed)
  float* wA    = ws + (size_t)RST*NE;                 // NE
  float* wB    = wA + NE;                             // NE
  float* partA = wB + NE;                             // KMAX * NBLK
  float* partB = partA + KMAX*NBLK;                   // KMAX * NBLK
  float* partN = partB + KMAX*NBLK;                   // NBLK
  float* scal  = partN + NBLK;                        // 640 floats

  hipMemcpyAsync(x, guess, (size_t)NE*sizeof(float), hipMemcpyDeviceToDevice, stream);

  dim3 g(NBLK), blk(TPB);
  for (int cyc = 0; cyc < NCYC; ++cyc) {
    k_resid<<<g, blk, 0, stream>>>(b, x, wA, partN);
#define STEP(J) \
    { float* win  = ((J) & 1) ? wB : wA;  float* wout = ((J) & 1) ? wA : wB; \
      k_S<J><<<g, blk, 0, stream>>>(win, wout, V, partN, partA, scal); \
      k_P<J><<<g, blk, 0, stream>>>(wout, V, partA, partB, scal); \
      k_Q<J><<<g, blk, 0, stream>>>(wout, V, partB, partN, scal); }
    STEP(0)  STEP(1)  STEP(2)  STEP(3)
    STEP(4)  STEP(5)  STEP(6)  STEP(7)
    STEP(8)  STEP(9)  STEP(10) STEP(11)
    STEP(12) STEP(13) STEP(14) STEP(15)
#undef STEP
    k_solve<<<1, 256, 0, stream>>>(partN, scal);
    k_update_x<<<g, blk, 0, stream>>>(V, scal, x);
  }
}